// Round 8
// baseline (114.341 us; speedup 1.0000x reference)
//
#include <hip/hip_runtime.h>

// AdaptiveAngleConv round 8: 16-wave persistent blocks (4 waves/SIMD), full-width
// row ring, bias folded into a 37th K-step, lgkm-only barriers, NT stores.
// 256 blocks x 1024 thr (1/CU). Waves = (angle, row01, whalf01); wave M=64 x N=64.

#define CIN 64
#define COUT 64
#define HH 128
#define WW 128
#define NB 16
#define HW (HH*WW)

typedef short bf16x8 __attribute__((ext_vector_type(8)));
typedef float f32x16 __attribute__((ext_vector_type(16)));

// xs: ring of 4 full-width rows. byte(slot, ci, wI) = XS_OFF + slot*XS_ROW +
//   (ci>>3)*XS_SLOT + wI*16 + (ci&7)*2 ; wI 0..129 = x col -1..128.
// wI 0 and 129 are permanently-zero (image border), written once.
#define XS_SLOT 2080
#define XS_ROW  16640
#define XS_OFF  75776               // A region: 37 kc * 2048 B
#define LDS_BYTES (XS_OFF + 4 * XS_ROW)   // 142,336 B

// Per weight-tap s: paired x-tap t = INV_a[s]; dh index and dw*16 bytes (R7-validated).
__device__ __constant__ unsigned char DHI_d[4][9] = {
  {0,0,0,1,1,1,2,2,2},
  {0,0,1,0,1,2,1,2,2},
  {0,1,2,0,1,2,0,1,2},
  {1,2,2,0,1,2,0,0,1},
};
__device__ __constant__ unsigned short DWB_d[4][9] = {
  {0,16,32,0,16,32,0,16,32},
  {16,32,32,0,16,32,0,0,16},
  {32,32,32,16,16,16,0,0,0},
  {32,32,16,32,16,0,16,0,0},
};

static __device__ __forceinline__ unsigned short f2bf(float f) {
  unsigned u = __builtin_bit_cast(unsigned, f);
  return (unsigned short)((u + 0x7FFFu + ((u >> 16) & 1u)) >> 16);
}
static __device__ __forceinline__ unsigned pk2(float lo, float hi) {
  return (unsigned)f2bf(lo) | ((unsigned)f2bf(hi) << 16);
}

// Canonical A + bias row: e = ((kc*2 + half)*64 + cm)*8 + j ; kc 0..36.
// kc<36: ci = (kc&3)*16 + half*8 + j ; value W[cm][ci][kc>>2].
// kc==36: bias[cm] one-hot at (half==0, j==0)  -> MFMA with one-hot B adds bias.
__global__ void build_A_kernel(const float* __restrict__ wgt,
                               const float* __restrict__ bias,
                               unsigned short* __restrict__ A) {
  const int e = blockIdx.x * 256 + threadIdx.x;   // 37,888 total
  const int j = e & 7;
  const int cm = (e >> 3) & 63;
  const int half = (e >> 9) & 1;
  const int kc = e >> 10;
  if (kc < 36) {
    const int s = kc >> 2, q = kc & 3;
    const int ci = q * 16 + half * 8 + j;
    A[e] = f2bf(wgt[(cm * CIN + ci) * 9 + s]);
  } else {
    A[e] = (half == 0 && j == 0) ? f2bf(bias[cm]) : (unsigned short)0;
  }
}

static __device__ __forceinline__ void lgkm_barrier() {
  asm volatile("s_waitcnt lgkmcnt(0)" ::: "memory");
  __builtin_amdgcn_s_barrier();
}

__global__ __launch_bounds__(1024) void aconv_v8_kernel(
    const float* __restrict__ x,              // [B][CIN][H][W] fp32
    const unsigned short* __restrict__ Ag,    // canonical W + bias kc, 37,888 bf16
    float* __restrict__ out)                  // [4][B][COUT][H][W] fp32
{
  __shared__ __align__(16) unsigned char lds[LDS_BYTES];

  const int tid = threadIdx.x;
  const int lane = tid & 63;
  const int wid = tid >> 6;         // 16 waves
  const int a   = wid >> 2;         // angle
  const int row = (wid >> 1) & 1;   // output row within 2-row tile
  const int wh  = wid & 1;          // w half
  const int half = lane >> 5;
  const int ln = lane & 31;

  const int blk = blockIdx.x;       // 256 = 16 b x 16 rem
  const int b   = blk >> 4;
  const int rem = blk & 15;
  const int hbase = rem * 8;

  int dhi[9]; unsigned dwb[9];
  #pragma unroll
  for (int s = 0; s < 9; ++s) { dhi[s] = DHI_d[a][s]; dwb[s] = DWB_d[a][s]; }

  // ---- stage canonical A (75,776 B) ----
  {
    const uint4* Ag4 = (const uint4*)Ag;
    uint4* As4 = (uint4*)lds;
    #pragma unroll
    for (int i = 0; i < 5; ++i) {
      const int g = tid + i * 1024;
      if (g < 4736) As4[g] = Ag4[g];
    }
  }
  // ---- zero permanent w-halo (wI = 0, 129) for all 4 row slots ----
  if (tid < 64) {
    const int rs = tid >> 4, cs = (tid >> 1) & 7, side = tid & 1;
    uint4 z = {0u, 0u, 0u, 0u};
    *(uint4*)(lds + XS_OFF + rs * XS_ROW + cs * XS_SLOT + side * 129 * 16) = z;
  }

  // ---- per-thread staging geometry: thread -> (cs, wc); granule = 8 ci x 1 col ----
  const int scs = (tid >> 7) & 7;   // ci slot 0..7
  const int swc = tid & 127;        // x col 0..127
  const float* sxb = x + (size_t)(b * CIN + scs * 8) * HW + swc;
  const unsigned sdstb = (unsigned)(XS_OFF + scs * XS_SLOT + (1 + swc) * 16);

  // ---- prologue: rows hbase-1..hbase+2 -> slots 0..3 ----
  {
    float pv[4][8];
    #pragma unroll
    for (int rr = 0; rr < 4; ++rr) {
      const int gh = hbase - 1 + rr;
      const bool inb = (unsigned)gh < HH;
      const float* xp = sxb + (size_t)gh * WW;
      #pragma unroll
      for (int q = 0; q < 8; ++q) pv[rr][q] = inb ? xp[(size_t)q * HW] : 0.f;
    }
    #pragma unroll
    for (int rr = 0; rr < 4; ++rr) {
      uint4 u;
      u.x = pk2(pv[rr][0], pv[rr][1]); u.y = pk2(pv[rr][2], pv[rr][3]);
      u.z = pk2(pv[rr][4], pv[rr][5]); u.w = pk2(pv[rr][6], pv[rr][7]);
      *(uint4*)(lds + sdstb + rr * XS_ROW) = u;
    }
  }
  __syncthreads();

  const unsigned char* Asb = lds + (unsigned)(half * 1024 + ln * 16);
  const unsigned char* Bsb = lds + XS_OFF + (unsigned)(half * XS_SLOT + (wh * 64 + ln) * 16);

  // one-hot B fragment for the bias K-step (k = 0 only)
  bf16x8 ob = (bf16x8)(short)0;
  if (half == 0) ob[0] = (short)0x3F80;

  #pragma unroll 1
  for (int it = 0; it < 4; ++it) {
    const bool pf = (it < 3);

    // per-tile B row offsets: x row h0+row+dh-1 -> slot (it*2+row+dh)&3
    unsigned boff_t[9];
    {
      unsigned rowoff[3];
      #pragma unroll
      for (int dh = 0; dh < 3; ++dh)
        rowoff[dh] = (unsigned)(((it * 2 + row + dh) & 3) * XS_ROW);
      #pragma unroll
      for (int s = 0; s < 9; ++s) boff_t[s] = dwb[s] + rowoff[dhi[s]];
    }

    // issue next 2 rows' loads (rows hbase+2*it+3 + rr)
    float gv[2][8];
    if (pf) {
      #pragma unroll
      for (int rr = 0; rr < 2; ++rr) {
        const int gh = hbase + it * 2 + 3 + rr;
        const bool inb = (unsigned)gh < HH;
        const float* xp = sxb + (size_t)gh * WW;
        #pragma unroll
        for (int q = 0; q < 8; ++q) gv[rr][q] = inb ? xp[(size_t)q * HW] : 0.f;
      }
    }

    f32x16 acc[2][2];
    #pragma unroll
    for (int mf = 0; mf < 2; ++mf)
      #pragma unroll
      for (int nf = 0; nf < 2; ++nf) acc[mf][nf] = (f32x16)(0.f);

    auto kstep = [&](int kc) {
      const bf16x8 af0 = *(const bf16x8*)(Asb + kc * 2048);
      const bf16x8 af1 = *(const bf16x8*)(Asb + kc * 2048 + 512);
      const unsigned bb = boff_t[kc >> 2] + (unsigned)((kc & 3) * 2 * XS_SLOT);
      const bf16x8 bf0 = *(const bf16x8*)(Bsb + bb);
      const bf16x8 bf1 = *(const bf16x8*)(Bsb + bb + 512);
      acc[0][0] = __builtin_amdgcn_mfma_f32_32x32x16_bf16(af0, bf0, acc[0][0], 0, 0, 0);
      acc[0][1] = __builtin_amdgcn_mfma_f32_32x32x16_bf16(af0, bf1, acc[0][1], 0, 0, 0);
      acc[1][0] = __builtin_amdgcn_mfma_f32_32x32x16_bf16(af1, bf0, acc[1][0], 0, 0, 0);
      acc[1][1] = __builtin_amdgcn_mfma_f32_32x32x16_bf16(af1, bf1, acc[1][1], 0, 0, 0);
    };

    #pragma unroll
    for (int kc = 0; kc < 18; ++kc) kstep(kc);

    // pack staged rows (loads have landed under K first half)
    uint4 gp[2];
    if (pf) {
      #pragma unroll
      for (int rr = 0; rr < 2; ++rr) {
        gp[rr].x = pk2(gv[rr][0], gv[rr][1]); gp[rr].y = pk2(gv[rr][2], gv[rr][3]);
        gp[rr].z = pk2(gv[rr][4], gv[rr][5]); gp[rr].w = pk2(gv[rr][6], gv[rr][7]);
      }
    }

    #pragma unroll
    for (int kc = 18; kc < 36; ++kc) kstep(kc);

    // bias K-step: one-hot B adds bias[cm] (kc=36 of A) to every column
    {
      const bf16x8 af0 = *(const bf16x8*)(Asb + 36 * 2048);
      const bf16x8 af1 = *(const bf16x8*)(Asb + 36 * 2048 + 512);
      acc[0][0] = __builtin_amdgcn_mfma_f32_32x32x16_bf16(af0, ob, acc[0][0], 0, 0, 0);
      acc[0][1] = __builtin_amdgcn_mfma_f32_32x32x16_bf16(af0, ob, acc[0][1], 0, 0, 0);
      acc[1][0] = __builtin_amdgcn_mfma_f32_32x32x16_bf16(af1, ob, acc[1][0], 0, 0, 0);
      acc[1][1] = __builtin_amdgcn_mfma_f32_32x32x16_bf16(af1, ob, acc[1][1], 0, 0, 0);
    }

    // nontemporal stores (drain under next K-loop)
    const int hout = hbase + it * 2 + row;
    #pragma unroll
    for (int mf = 0; mf < 2; ++mf)
      #pragma unroll
      for (int nf = 0; nf < 2; ++nf) {
        const f32x16 v = acc[mf][nf];
        float* op = out + (((size_t)(a * NB + b) * COUT + mf * 32 + 4 * half) * HH
                           + hout) * WW + wh * 64 + nf * 32 + ln;
        #pragma unroll
        for (int g = 0; g < 16; ++g)
          __builtin_nontemporal_store(v[g], op + (size_t)((g & 3) + 8 * (g >> 2)) * HW);
      }

    lgkm_barrier();                 // all waves' xs reads complete (no store drain)
    if (pf) {
      #pragma unroll
      for (int rr = 0; rr < 2; ++rr) {
        const unsigned slot = (unsigned)((it * 2 + 4 + rr) & 3);
        *(uint4*)(lds + sdstb + slot * XS_ROW) = gp[rr];
      }
    }
    lgkm_barrier();                 // new rows visible
  }
}

extern "C" void kernel_launch(void* const* d_in, const int* in_sizes, int n_in,
                              void* d_out, int out_size, void* d_ws, size_t ws_size,
                              hipStream_t stream) {
  const float* x    = (const float*)d_in[0];
  const float* wgt  = (const float*)d_in[1];
  const float* bias = (const float*)d_in[2];
  float* out = (float*)d_out;
  unsigned short* A = (unsigned short*)d_ws;   // 75,776 B

  build_A_kernel<<<148, 256, 0, stream>>>(wgt, bias, A);
  aconv_v8_kernel<<<256, 1024, 0, stream>>>(x, A, out);
}